// Round 2
// baseline (2429.242 us; speedup 1.0000x reference)
//
#include <hip/hip_runtime.h>
#include <cmath>

#define HH 128
#define WW 128
#define HWSZ (HH * WW)

static __device__ __forceinline__ int imin(int a, int b) { return a < b ? a : b; }
static __device__ __forceinline__ int imax(int a, int b) { return a > b ? a : b; }

// ---------------------------------------------------------------------------
// Weight transpose: w[cout][cin][3][3] -> wt[cin_pad][9][128] (zero padded)
// ---------------------------------------------------------------------------
__global__ void wtrans_kernel(const float* __restrict__ w, float* __restrict__ wt,
                              int cout, int cin, int cin_pad) {
  int idx = blockIdx.x * 256 + threadIdx.x;
  int total = cin_pad * 9 * 128;
  if (idx >= total) return;
  int co = idx & 127;
  int t  = (idx >> 7) % 9;
  int ci = idx / (9 * 128);
  float v = 0.f;
  if (co < cout && ci < cin) v = w[((size_t)co * cin + ci) * 9 + t];
  wt[idx] = v;
}

// ---------------------------------------------------------------------------
// Fused 3x3 conv (+bias, optional leaky-relu 0.1), stride 1, SAME padding.
// Block: 256 threads = 64-px row strip x all-COUT-tile(128).
// Per-thread: 4 cout x 8 px. K-loop: cin chunks of 8 x 9 taps via LDS.
// wt layout: [cin_pad][9][128].
// ---------------------------------------------------------------------------
__global__ __launch_bounds__(256) void conv3x3_kernel(
    const float* __restrict__ in, const float* __restrict__ wt,
    const float* __restrict__ bias, float* __restrict__ out,
    int cin, int nch, int cout, int lrelu) {
  __shared__ __align__(16) float s_in[8 * 3 * 68];   // [cl][row][68] (col0 = x0-1)
  __shared__ __align__(16) float s_w[8 * 9 * 128];   // [cl][tap][co]

  const int tid = threadIdx.x;
  const int x0 = blockIdx.x * 64;
  const int y  = blockIdx.y;
  const int b  = blockIdx.z;
  const int px0 = (tid & 7) * 8;        // 8 px groups x 8 px
  const int co0 = (tid >> 3) * 4;       // 32 co groups x 4 co

  float acc[4][8];
#pragma unroll
  for (int i = 0; i < 4; ++i)
#pragma unroll
    for (int j = 0; j < 8; ++j) acc[i][j] = 0.f;

  for (int ch = 0; ch < nch; ++ch) {
    const int c0 = ch * 8;
    __syncthreads();
    // ---- stage input tile: 8 cin x 3 rows x 66 cols (zero padded borders)
    for (int idx = tid; idx < 8 * 3 * 66; idx += 256) {
      int cl  = idx / 198;
      int rem = idx - cl * 198;
      int r   = rem / 66;
      int col = rem - r * 66;
      int c = c0 + cl;
      int gy = y + r - 1;
      int gx = x0 + col - 1;
      float v = 0.f;
      if (c < cin && (unsigned)gy < (unsigned)HH && (unsigned)gx < (unsigned)WW)
        v = in[(((size_t)b * cin + c) * HH + gy) * WW + gx];
      s_in[(cl * 3 + r) * 68 + col] = v;
    }
    // ---- stage weights: 8 cin x 9 taps x 128 co (contiguous copy)
    {
      const float* wtp = wt + (size_t)c0 * 9 * 128;
      for (int idx = tid; idx < 8 * 9 * 128; idx += 256) s_w[idx] = wtp[idx];
    }
    __syncthreads();
    // ---- rank-1 updates
#pragma unroll
    for (int cl = 0; cl < 8; ++cl) {
#pragma unroll
      for (int di = 0; di < 3; ++di) {
        const float* rp = &s_in[(cl * 3 + di) * 68 + px0];
        float4 a0 = *(const float4*)rp;
        float4 a1 = *(const float4*)(rp + 4);
        float2 a2 = *(const float2*)(rp + 8);
        float in10[10] = {a0.x, a0.y, a0.z, a0.w, a1.x, a1.y, a1.z, a1.w, a2.x, a2.y};
#pragma unroll
        for (int dj = 0; dj < 3; ++dj) {
          float4 wv = *(const float4*)&s_w[(cl * 9 + di * 3 + dj) * 128 + co0];
          float wr[4] = {wv.x, wv.y, wv.z, wv.w};
#pragma unroll
          for (int cc = 0; cc < 4; ++cc)
#pragma unroll
            for (int p = 0; p < 8; ++p)
              acc[cc][p] += wr[cc] * in10[p + dj];
        }
      }
    }
  }

  // ---- epilogue
#pragma unroll
  for (int cc = 0; cc < 4; ++cc) {
    const int co = co0 + cc;
    if (co < cout) {
      const float bv = bias[co];
      float v[8];
#pragma unroll
      for (int p = 0; p < 8; ++p) {
        float t = acc[cc][p] + bv;
        if (lrelu) t = (t >= 0.f) ? t : 0.1f * t;
        v[p] = t;
      }
      float* op = out + (((size_t)b * cout + co) * HH + y) * WW + x0 + px0;
      *(float4*)op       = make_float4(v[0], v[1], v[2], v[3]);
      *(float4*)(op + 4) = make_float4(v[4], v[5], v[6], v[7]);
    }
  }
}

// ---------------------------------------------------------------------------
// Modulated deformable conv 3x3 (stride 1, pad 1, dil 1) with fused
// offset = 3*tanh(head[0:18]) + flow flipped, mask = sigmoid(head[18:27]).
// Block: 128 threads = 64-px row strip x 128 cout; per-thread 8co x 8px.
// K-loop: cin chunks of 4 x 9 taps. Bilinear samples staged in LDS.
// wt layout: [cin][9][128].
// ---------------------------------------------------------------------------
__global__ __launch_bounds__(128) void deform_kernel(
    const float* __restrict__ x, const float* __restrict__ head,
    const float* __restrict__ flow, const float* __restrict__ wt,
    const float* __restrict__ bias, float* __restrict__ out) {
  __shared__ __align__(16) float s_s[4 * 9 * 64];    // [cl][tap][px]
  __shared__ __align__(16) float s_w[4 * 9 * 128];   // [cl][tap][co]

  const int tid = threadIdx.x;
  const int x0 = blockIdx.x * 64;
  const int y  = blockIdx.y;
  const int b  = blockIdx.z;
  const int px0 = (tid & 7) * 8;        // 8 px groups x 8 px
  const int co0 = (tid >> 3) * 8;       // 16 co groups x 8 co

  // ---- per-(tap,px) pair precompute: 9*64 = 576 pairs over 128 threads
  int   p_i00[5], p_i01[5], p_i10[5], p_i11[5], p_sb[5];
  float p_w00[5], p_w01[5], p_w10[5], p_w11[5];
#pragma unroll
  for (int i = 0; i < 5; ++i) {
    const int pid = tid + i * 128;
    const bool act = (i < 4) || (tid < 64);
    p_w00[i] = p_w01[i] = p_w10[i] = p_w11[i] = 0.f;
    p_i00[i] = p_i01[i] = p_i10[i] = p_i11[i] = 0;
    p_sb[i] = 0;
    if (act) {
      const int k  = pid >> 6;          // 0..8
      const int px = pid & 63;
      const int gx = x0 + px;
      const size_t pix = (size_t)y * WW + gx;
      const float* hb = head + (size_t)b * 27 * HWSZ;
      const float hy = hb[(size_t)(2 * k) * HWSZ + pix];
      const float hx = hb[(size_t)(2 * k + 1) * HWSZ + pix];
      const float hm = hb[(size_t)(18 + k) * HWSZ + pix];
      const float* fb = flow + (size_t)b * 2 * HWSZ;
      const float fly = fb[HWSZ + pix];   // flow[:,1] -> dy
      const float flx = fb[pix];          // flow[:,0] -> dx
      const float dy = 3.f * tanhf(hy) + fly;
      const float dx = 3.f * tanhf(hx) + flx;
      const float py  = (float)(y - 1 + (k / 3)) + dy;
      const float pxx = (float)(gx - 1 + (k % 3)) + dx;
      const float y0f = floorf(py), x0f = floorf(pxx);
      const float fy = py - y0f, fx = pxx - x0f;
      const int iy0 = (int)y0f, ix0 = (int)x0f;
      const int iy1 = iy0 + 1,  ix1 = ix0 + 1;
      const float m = 1.f / (1.f + expf(-hm));   // sigmoid mask folded in
      const float vy0 = (iy0 >= 0 && iy0 < HH) ? m : 0.f;
      const float vy1 = (iy1 >= 0 && iy1 < HH) ? m : 0.f;
      const float vx0 = (ix0 >= 0 && ix0 < WW) ? 1.f : 0.f;
      const float vx1 = (ix1 >= 0 && ix1 < WW) ? 1.f : 0.f;
      p_w00[i] = (1.f - fy) * (1.f - fx) * vy0 * vx0;
      p_w01[i] = (1.f - fy) * fx * vy0 * vx1;
      p_w10[i] = fy * (1.f - fx) * vy1 * vx0;
      p_w11[i] = fy * fx * vy1 * vx1;
      const int cy0 = imin(imax(iy0, 0), HH - 1);
      const int cy1 = imin(imax(iy1, 0), HH - 1);
      const int cx0 = imin(imax(ix0, 0), WW - 1);
      const int cx1 = imin(imax(ix1, 0), WW - 1);
      p_i00[i] = cy0 * WW + cx0;
      p_i01[i] = cy0 * WW + cx1;
      p_i10[i] = cy1 * WW + cx0;
      p_i11[i] = cy1 * WW + cx1;
      p_sb[i] = k * 64 + px;
    }
  }

  float acc[8][8];
#pragma unroll
  for (int i = 0; i < 8; ++i)
#pragma unroll
    for (int j = 0; j < 8; ++j) acc[i][j] = 0.f;

  for (int ch = 0; ch < 32; ++ch) {
    const int c0 = ch * 4;
    __syncthreads();
    // ---- stage weights for 4 cin (contiguous 4608 floats)
    {
      const float* wp = wt + (size_t)c0 * 9 * 128;
      for (int idx = tid; idx < 4 * 9 * 128; idx += 128) s_w[idx] = wp[idx];
    }
    // ---- bilinear sampling into s_s[cl][tap][px]
    {
      const float* xb = x + ((size_t)b * 128 + c0) * HWSZ;
#pragma unroll
      for (int i = 0; i < 5; ++i) {
        if (i < 4 || tid < 64) {
#pragma unroll
          for (int cl = 0; cl < 4; ++cl) {
            const float* xp = xb + (size_t)cl * HWSZ;
            float v = p_w00[i] * xp[p_i00[i]] + p_w01[i] * xp[p_i01[i]] +
                      p_w10[i] * xp[p_i10[i]] + p_w11[i] * xp[p_i11[i]];
            s_s[cl * 576 + p_sb[i]] = v;
          }
        }
      }
    }
    __syncthreads();
    // ---- einsum rank-1 updates
#pragma unroll
    for (int cl = 0; cl < 4; ++cl) {
#pragma unroll
      for (int k = 0; k < 9; ++k) {
        const int rk = cl * 9 + k;
        float4 wv0 = *(const float4*)&s_w[rk * 128 + co0];
        float4 wv1 = *(const float4*)&s_w[rk * 128 + co0 + 4];
        float4 sa  = *(const float4*)&s_s[rk * 64 + px0];
        float4 sb4 = *(const float4*)&s_s[rk * 64 + px0 + 4];
        float wr[8] = {wv0.x, wv0.y, wv0.z, wv0.w, wv1.x, wv1.y, wv1.z, wv1.w};
        float sv[8] = {sa.x, sa.y, sa.z, sa.w, sb4.x, sb4.y, sb4.z, sb4.w};
#pragma unroll
        for (int cc = 0; cc < 8; ++cc)
#pragma unroll
          for (int p = 0; p < 8; ++p)
            acc[cc][p] += wr[cc] * sv[p];
      }
    }
  }

  // ---- epilogue
#pragma unroll
  for (int cc = 0; cc < 8; ++cc) {
    const int co = co0 + cc;
    const float bv = bias[co];
    float v[8];
#pragma unroll
    for (int p = 0; p < 8; ++p) v[p] = acc[cc][p] + bv;
    float* op = out + (((size_t)b * 128 + co) * HH + y) * WW + x0 + px0;
    *(float4*)op       = make_float4(v[0], v[1], v[2], v[3]);
    *(float4*)(op + 4) = make_float4(v[4], v[5], v[6], v[7]);
  }
}

// ---------------------------------------------------------------------------
// Launch
// ---------------------------------------------------------------------------
extern "C" void kernel_launch(void* const* d_in, const int* in_sizes, int n_in,
                              void* d_out, int out_size, void* d_ws, size_t ws_size,
                              hipStream_t stream) {
  const float* x    = (const float*)d_in[0];
  const float* cond = (const float*)d_in[1];
  const float* flow = (const float*)d_in[2];
  const float* w1 = (const float*)d_in[3];
  const float* b1 = (const float*)d_in[4];
  const float* w2 = (const float*)d_in[5];
  const float* b2 = (const float*)d_in[6];
  const float* w3 = (const float*)d_in[7];
  const float* b3 = (const float*)d_in[8];
  const float* w4 = (const float*)d_in[9];
  const float* b4 = (const float*)d_in[10];
  const float* wd = (const float*)d_in[11];
  const float* bd = (const float*)d_in[12];
  float* out = (float*)d_out;
  float* ws  = (float*)d_ws;

  // workspace layout (floats)
  // head aliases f2: f2 is dead after conv3 reads it; conv4 then writes head.
  float* f1    = ws;                       // 4*128*128*128 = 8388608
  float* f2    = f1 + 8388608;             // 8388608
  float* headb = f2;                       // 4*27*16384 = 1769472 (aliases f2)
  float* wt1   = f2 + 8388608;             // 264*9*128 = 304128
  float* wt2   = wt1 + 304128;             // 147456
  float* wt3   = wt2 + 147456;             // 147456
  float* wt4   = wt3 + 147456;             // 147456 (cout 27 zero-padded)
  float* wtd   = wt4 + 147456;             // 147456
  // total: 17,671,168 floats = 70.7 MB

  dim3 blk256(256), blk128(128);

  // weight transposes (tiny)
  {
    int t1 = 264 * 9 * 128;
    hipLaunchKernelGGL(wtrans_kernel, dim3((t1 + 255) / 256), blk256, 0, stream, w1, wt1, 128, 261, 264);
    int t2 = 128 * 9 * 128;
    hipLaunchKernelGGL(wtrans_kernel, dim3((t2 + 255) / 256), blk256, 0, stream, w2, wt2, 128, 128, 128);
    hipLaunchKernelGGL(wtrans_kernel, dim3((t2 + 255) / 256), blk256, 0, stream, w3, wt3, 128, 128, 128);
    hipLaunchKernelGGL(wtrans_kernel, dim3((t2 + 255) / 256), blk256, 0, stream, w4, wt4, 27, 128, 128);
    hipLaunchKernelGGL(wtrans_kernel, dim3((t2 + 255) / 256), blk256, 0, stream, wd, wtd, 128, 128, 128);
  }

  dim3 cgrid(WW / 64, HH, 4);
  // conv1: cond(261) -> f1, lrelu
  hipLaunchKernelGGL(conv3x3_kernel, cgrid, blk256, 0, stream, cond, wt1, b1, f1, 261, 33, 128, 1);
  // conv2: f1 -> f2, lrelu
  hipLaunchKernelGGL(conv3x3_kernel, cgrid, blk256, 0, stream, f1, wt2, b2, f2, 128, 16, 128, 1);
  // conv3: f2 -> f1, lrelu
  hipLaunchKernelGGL(conv3x3_kernel, cgrid, blk256, 0, stream, f2, wt3, b3, f1, 128, 16, 128, 1);
  // conv4 (head): f1 -> headb (aliases f2, safe: f2 dead), no activation
  hipLaunchKernelGGL(conv3x3_kernel, cgrid, blk256, 0, stream, f1, wt4, b4, headb, 128, 16, 27, 0);
  // deformable conv
  hipLaunchKernelGGL(deform_kernel, dim3(WW / 64, HH, 4), blk128, 0, stream, x, headb, flow, wtd, bd, out);
}